// Round 19
// baseline (299.696 us; speedup 1.0000x reference)
//
#include <hip/hip_runtime.h>
#include <hip/hip_bf16.h>
#include <stdint.h>

#define B_ 4
#define T_ 256
#define U_ 128
#define EH_ 1024
#define PH_ 640
#define JH_ 640
#define V_ 1024
#define KT_ 20   // JH / 32 K-tiles

typedef short bf16x8 __attribute__((ext_vector_type(8)));
typedef float f32x4 __attribute__((ext_vector_type(4)));
typedef unsigned short u16;

__device__ __forceinline__ u16 f2bf(float f) {
  union { float f; uint32_t u; } v;
  v.f = f;
  uint32_t u = v.u;
  return (u16)((u + 0x7FFFu + ((u >> 16) & 1u)) >> 16);
}

// HW packed fp32->bf16 (RNE), lo = src0
__device__ __forceinline__ uint32_t cvt2(float lo, float hi) {
  uint32_t r;
  asm("v_cvt_pk_bf16_f32 %0, %1, %2" : "=v"(r) : "v"(lo), "v"(hi));
  return r;
}

#define LGKM0  asm volatile("s_waitcnt lgkmcnt(0)" ::: "memory")

// ---------------------------------------------------------------------------
// Transpose + fp32->bf16: in [batch][H][W] -> out [batch][W][H]
// ---------------------------------------------------------------------------
__global__ void k_transpose_cvt(const float* __restrict__ in, u16* __restrict__ out,
                                int H, int W) {
  __shared__ float tile[32][33];
  int b = blockIdx.z;
  int h0 = blockIdx.y * 32, w0 = blockIdx.x * 32;
  const float* pin = in + (size_t)b * H * W;
  u16* pout = out + (size_t)b * H * W;
  int lw = threadIdx.x & 31, lh = threadIdx.x >> 5;
#pragma unroll
  for (int i = 0; i < 4; i++) {
    int h = lh + i * 8;
    tile[h][lw] = pin[(size_t)(h0 + h) * W + (w0 + lw)];
  }
  __syncthreads();
#pragma unroll
  for (int i = 0; i < 4; i++) {
    int w = lh + i * 8;
    pout[(size_t)(w0 + w) * H + (h0 + lw)] = f2bf(tile[lw][w]);
  }
}

// ---------------------------------------------------------------------------
// Merged weight prep: cvt W_enc, cvt W_pred, pack W_out (one launch)
// Wpk u16-index = ((t*4 + g)*1024 + c)*8 + j  ==  W_out[c][t*32 + g*8 + j]
// ---------------------------------------------------------------------------
__global__ void k_prep_w(const float* __restrict__ We, const float* __restrict__ Wp,
                         const float* __restrict__ Wo,
                         u16* __restrict__ WeB, u16* __restrict__ WpB,
                         u16* __restrict__ Wpk) {
  int s = blockIdx.x * 256 + threadIdx.x;
  if (s < 163840) {                       // W_enc: 655360 elems / 4
    int idx = s * 4;
    float4 v = *(const float4*)(We + idx);
    ushort4 o;
    o.x = f2bf(v.x); o.y = f2bf(v.y); o.z = f2bf(v.z); o.w = f2bf(v.w);
    *(ushort4*)(WeB + idx) = o;
  } else if (s < 266240) {                // W_pred: 409600 / 4
    int idx = (s - 163840) * 4;
    float4 v = *(const float4*)(Wp + idx);
    ushort4 o;
    o.x = f2bf(v.x); o.y = f2bf(v.y); o.z = f2bf(v.z); o.w = f2bf(v.w);
    *(ushort4*)(WpB + idx) = o;
  } else {                                // pack W_out: 81920 slots
    int q = s - 266240;
    int c = q & 1023;
    int g = (q >> 10) & 3;
    int t = q >> 12;
    const float* src = Wo + (size_t)c * JH_ + t * 32 + g * 8;
    float4 a = *(const float4*)src;
    float4 b2 = *(const float4*)(src + 4);
    ushort4 lo, hi;
    lo.x = f2bf(a.x);  lo.y = f2bf(a.y);  lo.z = f2bf(a.z);  lo.w = f2bf(a.w);
    hi.x = f2bf(b2.x); hi.y = f2bf(b2.y); hi.z = f2bf(b2.z); hi.w = f2bf(b2.w);
    u16* d = Wpk + (size_t)q * 8;
    *(ushort4*)d = lo;
    *(ushort4*)(d + 4) = hi;
  }
}

// ---------------------------------------------------------------------------
// Projection GEMM: C[m][n] = sum_k A[m][k]*Bm[n][k] + bias[n]
// PACK=0: C fp32 [M][N] row-major. PACK=1: pPk layout (strideC=81920).
// ---------------------------------------------------------------------------
template<int PACK>
__global__ void k_proj_gemm(const u16* __restrict__ A, const u16* __restrict__ Bm,
                            const float* __restrict__ bias, float* __restrict__ C,
                            int K, int N, size_t strideA, size_t strideC) {
  __shared__ __align__(16) u16 sA[64 * 64];
  __shared__ __align__(16) u16 sB[64 * 64];
  int bb = blockIdx.z;
  const u16* Ab = A + (size_t)bb * strideA;
  float* Cb = C + (size_t)bb * strideC;
  int m0 = blockIdx.x * 64, n0 = blockIdx.y * 64;
  int tid = threadIdx.x;
  int lane = tid & 63, wid = tid >> 6;

  f32x4 acc[2][2] = {};
  for (int kk = 0; kk < K; kk += 64) {
#pragma unroll
    for (int i = 0; i < 2; i++) {
      int c = tid + i * 256;
      int r = c >> 3, kc = c & 7;
      int s = (r << 3) | (kc ^ (r & 7));
      *(bf16x8*)(sA + s * 8) = *(const bf16x8*)(Ab + (size_t)(m0 + r) * K + kk + kc * 8);
      *(bf16x8*)(sB + s * 8) = *(const bf16x8*)(Bm + (size_t)(n0 + r) * K + kk + kc * 8);
    }
    __syncthreads();
    int wr = (wid >> 1) * 32, wc = (wid & 1) * 32;
    int lr = lane & 15, lk = lane >> 4;
#pragma unroll
    for (int ki = 0; ki < 2; ki++) {
      bf16x8 af[2], bq[2];
#pragma unroll
      for (int mf = 0; mf < 2; mf++) {
        int r = wr + mf * 16 + lr;
        int kc = ki * 4 + lk;
        int s = (r << 3) | (kc ^ (r & 7));
        af[mf] = *(const bf16x8*)(sA + s * 8);
      }
#pragma unroll
      for (int nf = 0; nf < 2; nf++) {
        int r = wc + nf * 16 + lr;
        int kc = ki * 4 + lk;
        int s = (r << 3) | (kc ^ (r & 7));
        bq[nf] = *(const bf16x8*)(sB + s * 8);
      }
#pragma unroll
      for (int mf = 0; mf < 2; mf++)
#pragma unroll
        for (int nf = 0; nf < 2; nf++)
          acc[mf][nf] = __builtin_amdgcn_mfma_f32_16x16x32_bf16(af[mf], bq[nf], acc[mf][nf], 0, 0, 0);
    }
    __syncthreads();
  }
  int wr = (wid >> 1) * 32, wc = (wid & 1) * 32;
  int lr = lane & 15, lq = lane >> 4;
#pragma unroll
  for (int nf = 0; nf < 2; nf++) {
    int n = n0 + wc + nf * 16 + lr;
    float bv = bias[n];
#pragma unroll
    for (int mf = 0; mf < 2; mf++) {
#pragma unroll
      for (int r = 0; r < 4; r++) {
        int m = m0 + wr + mf * 16 + lq * 4 + r;
        float v = acc[mf][nf][r] + bv;
        if (PACK)
          Cb[(size_t)(m >> 6) * 40960 + (n >> 2) * 256 + (m & 63) * 4 + (n & 3)] = v;
        else
          Cb[(size_t)m * N + n] = v;
      }
    }
  }
}

// ---------------------------------------------------------------------------
// Fused joint GEMM + bias + log_softmax (round-14/17 champion + NT stores):
//   out[m][v] = log_softmax_v( relu(e[bt,:]+p[b,u,:]) . W_out[v,:] + b_out[v] )
// 64 rows x V=1024 per block (2048 blocks); 512 thr = 8 waves; wave wn owns
// cols [128wn,128wn+128). B streams to regs (dbuf, 1 tile ahead, wave-
// private cols). A built in LDS 2-tile chunks (one LGKM0+barrier per 2
// tiles). mfma(bq, af) -> C^T frags -> 32 NON-TEMPORAL dwordx4 stores
// (output is write-once; nt keeps the 537MB stream from evicting Wpk/p
// in L2). No rotation (r14); no persistence (refuted r11/r13/r16);
// 8-wave/256-reg point is the empirical optimum (r15/r18 both regressed).
// ---------------------------------------------------------------------------
__global__ __launch_bounds__(512)
void k_fused7(const float* __restrict__ e, const float* __restrict__ pPk,
              const u16* __restrict__ Wpk, const float* __restrict__ bout,
              float* __restrict__ out) {
  __shared__ __align__(16) u16 sA[2][4096];    // [chunk][tin<2][koct<4][64 rows][8]
  __shared__ __align__(16) float sE[JH_];
  __shared__ float redm[512];
  __shared__ float reds[512];

  int bid = blockIdx.x;
  int btile = bid >> 1, half = bid & 1, b = btile >> 8;
  int tid = threadIdx.x, lane = tid & 63, wn = tid >> 6;
  int lr = lane & 15, lk = lane >> 4;

  const float* eRow = e + (size_t)btile * JH_;
  const float* pPbase = pPk + ((size_t)(b * 2 + half) * 40960) + wn * 256 + lane * 4;
  const u16* wB = Wpk + ((size_t)lk * 1024 + wn * 128 + lr) * 8;
  float* outB = out + ((size_t)btile * U_ + half * 64) * V_;

  // A-build: thread (wn=k-quad, lane=row) writes 4 bf16 at:
  int awr = (wn >> 1) * 512 + lane * 8 + (wn & 1) * 4;

  f32x4 acc[4][8] = {};
  bf16x8 bq[2][8];

  auto loadB = [&](int t, bf16x8* d) {
#pragma unroll
    for (int nf = 0; nf < 8; nf++)
      d[nf] = *(const bf16x8*)(wB + (size_t)t * 32768 + nf * 128);
  };
  auto loadp = [&](int t) { return *(const float4*)(pPbase + t * 2048); };
  auto build = [&](int slot, int tin, int t, float4 pv) {
    float4 ev = *(const float4*)(&sE[t * 32 + wn * 4]);
    uint2 w;
    w.x = cvt2(fmaxf(pv.x + ev.x, 0.f), fmaxf(pv.y + ev.y, 0.f));
    w.y = cvt2(fmaxf(pv.z + ev.z, 0.f), fmaxf(pv.w + ev.w, 0.f));
    *(uint2*)(&sA[slot][tin * 2048 + awr]) = w;
  };

  // ---- prologue
  loadB(0, bq[0]);                            // earliest possible issue
  for (int i = tid; i < JH_; i += 512) sE[i] = eRow[i];
  float4 p0  = loadp(0);
  float4 p1  = loadp(1);
  float4 pcA = loadp(2);
  float4 pcB = loadp(3);
  float4 pnA = p0, pnB = p0;                  // init to silence undef
  LGKM0;
  __builtin_amdgcn_s_barrier();               // sE visible
  build(0, 0, 0, p0);
  build(0, 1, 1, p1);
  LGKM0;
  __builtin_amdgcn_s_barrier();               // A chunk 0 visible

#pragma unroll
  for (int t = 0; t < KT_; t++) {
    if (t + 1 < KT_) loadB(t + 1, bq[(t + 1) & 1]);
    if ((t & 1) == 0) {
      if (t + 4 < KT_) { pnA = loadp(t + 4); pnB = loadp(t + 5); }
      if (t + 2 < KT_) {
        int q1 = ((t >> 1) + 1) & 1;
        build(q1, 0, t + 2, pcA);
        build(q1, 1, t + 3, pcB);
      }
    }
    const u16* Ab = &sA[(t >> 1) & 1][(t & 1) * 2048 + lk * 512];
    bf16x8 af[4];
#pragma unroll
    for (int mf = 0; mf < 4; mf++)
      af[mf] = *(const bf16x8*)(Ab + (mf * 16 + lr) * 8);
    __builtin_amdgcn_s_setprio(1);
#pragma unroll
    for (int mf = 0; mf < 4; mf++)
#pragma unroll
      for (int nf = 0; nf < 8; nf++)
        acc[mf][nf] = __builtin_amdgcn_mfma_f32_16x16x32_bf16(bq[t & 1][nf], af[mf], acc[mf][nf], 0, 0, 0);
    __builtin_amdgcn_s_setprio(0);
    if ((t & 1) && t + 1 < KT_) {             // chunk boundary
      pcA = pnA; pcB = pnB;
      LGKM0;                                  // drain builds of next chunk
      __builtin_amdgcn_s_barrier();
    }
  }

  // ---- epilogue: C^T frags: row m=mf*16+lr, cols n=wn*128+nf*16+lk*4+[0..3]
#pragma unroll
  for (int nf = 0; nf < 8; nf++) {
    f32x4 bv = *(const f32x4*)(bout + wn * 128 + nf * 16 + lk * 4);
#pragma unroll
    for (int mf = 0; mf < 4; mf++) acc[mf][nf] += bv;
  }
  float gm[4], lsv[4];
#pragma unroll
  for (int mf = 0; mf < 4; mf++) {
    float m = acc[mf][0][0];
#pragma unroll
    for (int nf = 0; nf < 8; nf++)
#pragma unroll
      for (int j = 0; j < 4; j++) m = fmaxf(m, acc[mf][nf][j]);
    m = fmaxf(m, __shfl_xor(m, 16, 64));
    m = fmaxf(m, __shfl_xor(m, 32, 64));
    gm[mf] = m;
  }
  if (lane < 16) {
#pragma unroll
    for (int mf = 0; mf < 4; mf++) redm[(mf * 16 + lr) * 8 + wn] = gm[mf];
  }
  __syncthreads();
#pragma unroll
  for (int mf = 0; mf < 4; mf++) {
    float m = redm[(mf * 16 + lr) * 8];
#pragma unroll
    for (int w = 1; w < 8; w++) m = fmaxf(m, redm[(mf * 16 + lr) * 8 + w]);
    gm[mf] = m;
  }
#pragma unroll
  for (int mf = 0; mf < 4; mf++) {
    float s = 0.f;
#pragma unroll
    for (int nf = 0; nf < 8; nf++)
#pragma unroll
      for (int j = 0; j < 4; j++) s += __expf(acc[mf][nf][j] - gm[mf]);
    s += __shfl_xor(s, 16, 64);
    s += __shfl_xor(s, 32, 64);
    lsv[mf] = s;
  }
  if (lane < 16) {
#pragma unroll
    for (int mf = 0; mf < 4; mf++) reds[(mf * 16 + lr) * 8 + wn] = lsv[mf];
  }
  __syncthreads();
#pragma unroll
  for (int mf = 0; mf < 4; mf++) {
    float s = reds[(mf * 16 + lr) * 8];
#pragma unroll
    for (int w = 1; w < 8; w++) s += reds[(mf * 16 + lr) * 8 + w];
    lsv[mf] = gm[mf] + __logf(s);
  }

  // ---- 32 x NON-TEMPORAL dwordx4 stores (write-once stream, bypass L2 reuse)
#pragma unroll
  for (int mf = 0; mf < 4; mf++) {
    float* orow = outB + (size_t)(mf * 16 + lr) * V_ + wn * 128 + lk * 4;
#pragma unroll
    for (int nf = 0; nf < 8; nf++) {
      f32x4 v = acc[mf][nf] - lsv[mf];
      __builtin_nontemporal_store(v, (f32x4*)(orow + nf * 16));
    }
  }
}

// ---------------------------------------------------------------------------
extern "C" void kernel_launch(void* const* d_in, const int* in_sizes, int n_in,
                              void* d_out, int out_size, void* d_ws, size_t ws_size,
                              hipStream_t stream) {
  const float* enc    = (const float*)d_in[0];
  const float* dec    = (const float*)d_in[1];
  const float* W_enc  = (const float*)d_in[2];
  const float* b_enc  = (const float*)d_in[3];
  const float* W_pred = (const float*)d_in[4];
  const float* b_pred = (const float*)d_in[5];
  const float* W_out  = (const float*)d_in[6];
  const float* b_out  = (const float*)d_in[7];
  float* out = (float*)d_out;

  char* ws = (char*)d_ws;
  size_t off = 0;
  auto alloc = [&](size_t bytes) {
    void* pp = ws + off;
    off = (off + bytes + 255) & ~(size_t)255;
    return pp;
  };
  u16* encT   = (u16*)alloc((size_t)B_ * T_ * EH_ * 2);
  u16* decT   = (u16*)alloc((size_t)B_ * U_ * PH_ * 2);
  u16* WencB  = (u16*)alloc((size_t)JH_ * EH_ * 2);
  u16* WpredB = (u16*)alloc((size_t)JH_ * PH_ * 2);
  u16* Wpk    = (u16*)alloc((size_t)KT_ * 32768 * 2);
  float* eBuf = (float*)alloc((size_t)B_ * T_ * JH_ * 4);
  float* pPk  = (float*)alloc((size_t)81920 * 4 * 4);

  // front-end
  k_transpose_cvt<<<dim3(T_ / 32, EH_ / 32, B_), 256, 0, stream>>>(enc, encT, EH_, T_);
  k_transpose_cvt<<<dim3(U_ / 32, PH_ / 32, B_), 256, 0, stream>>>(dec, decT, PH_, U_);
  k_prep_w<<<1360, 256, 0, stream>>>(W_enc, W_pred, W_out, WencB, WpredB, Wpk);
  k_proj_gemm<0><<<dim3(T_ / 64, JH_ / 64, B_), 256, 0, stream>>>(
      encT, WencB, b_enc, eBuf, EH_, JH_, (size_t)T_ * EH_, (size_t)T_ * JH_);
  k_proj_gemm<1><<<dim3(U_ / 64, JH_ / 64, B_), 256, 0, stream>>>(
      decT, WpredB, b_pred, pPk, PH_, JH_, (size_t)U_ * PH_, (size_t)81920);

  // fused joint GEMM + log_softmax: one block per 64 output rows
  k_fused7<<<B_ * T_ * 2, 512, 0, stream>>>(eBuf, pPk, Wpk, b_out, out);
}

// Round 20
// 275.836 us; speedup vs baseline: 1.0865x; 1.0865x over previous
//
#include <hip/hip_runtime.h>
#include <hip/hip_bf16.h>
#include <stdint.h>

#define B_ 4
#define T_ 256
#define U_ 128
#define EH_ 1024
#define PH_ 640
#define JH_ 640
#define V_ 1024
#define KT_ 20   // JH / 32 K-tiles

typedef short bf16x8 __attribute__((ext_vector_type(8)));
typedef float f32x4 __attribute__((ext_vector_type(4)));
typedef unsigned short u16;

__device__ __forceinline__ u16 f2bf(float f) {
  union { float f; uint32_t u; } v;
  v.f = f;
  uint32_t u = v.u;
  return (u16)((u + 0x7FFFu + ((u >> 16) & 1u)) >> 16);
}

// HW packed fp32->bf16 (RNE), lo = src0
__device__ __forceinline__ uint32_t cvt2(float lo, float hi) {
  uint32_t r;
  asm("v_cvt_pk_bf16_f32 %0, %1, %2" : "=v"(r) : "v"(lo), "v"(hi));
  return r;
}

#define LGKM0  asm volatile("s_waitcnt lgkmcnt(0)" ::: "memory")

// ---------------------------------------------------------------------------
// Transpose + fp32->bf16: in [batch][H][W] -> out [batch][W][H]
// ---------------------------------------------------------------------------
__global__ void k_transpose_cvt(const float* __restrict__ in, u16* __restrict__ out,
                                int H, int W) {
  __shared__ float tile[32][33];
  int b = blockIdx.z;
  int h0 = blockIdx.y * 32, w0 = blockIdx.x * 32;
  const float* pin = in + (size_t)b * H * W;
  u16* pout = out + (size_t)b * H * W;
  int lw = threadIdx.x & 31, lh = threadIdx.x >> 5;
#pragma unroll
  for (int i = 0; i < 4; i++) {
    int h = lh + i * 8;
    tile[h][lw] = pin[(size_t)(h0 + h) * W + (w0 + lw)];
  }
  __syncthreads();
#pragma unroll
  for (int i = 0; i < 4; i++) {
    int w = lh + i * 8;
    pout[(size_t)(w0 + w) * H + (h0 + lw)] = f2bf(tile[lw][w]);
  }
}

// ---------------------------------------------------------------------------
// Merged weight prep: cvt W_enc, cvt W_pred, pack W_out (one launch)
// Wpk u16-index = ((t*4 + g)*1024 + c)*8 + j  ==  W_out[c][t*32 + g*8 + j]
// ---------------------------------------------------------------------------
__global__ void k_prep_w(const float* __restrict__ We, const float* __restrict__ Wp,
                         const float* __restrict__ Wo,
                         u16* __restrict__ WeB, u16* __restrict__ WpB,
                         u16* __restrict__ Wpk) {
  int s = blockIdx.x * 256 + threadIdx.x;
  if (s < 163840) {                       // W_enc: 655360 elems / 4
    int idx = s * 4;
    float4 v = *(const float4*)(We + idx);
    ushort4 o;
    o.x = f2bf(v.x); o.y = f2bf(v.y); o.z = f2bf(v.z); o.w = f2bf(v.w);
    *(ushort4*)(WeB + idx) = o;
  } else if (s < 266240) {                // W_pred: 409600 / 4
    int idx = (s - 163840) * 4;
    float4 v = *(const float4*)(Wp + idx);
    ushort4 o;
    o.x = f2bf(v.x); o.y = f2bf(v.y); o.z = f2bf(v.z); o.w = f2bf(v.w);
    *(ushort4*)(WpB + idx) = o;
  } else {                                // pack W_out: 81920 slots
    int q = s - 266240;
    int c = q & 1023;
    int g = (q >> 10) & 3;
    int t = q >> 12;
    const float* src = Wo + (size_t)c * JH_ + t * 32 + g * 8;
    float4 a = *(const float4*)src;
    float4 b2 = *(const float4*)(src + 4);
    ushort4 lo, hi;
    lo.x = f2bf(a.x);  lo.y = f2bf(a.y);  lo.z = f2bf(a.z);  lo.w = f2bf(a.w);
    hi.x = f2bf(b2.x); hi.y = f2bf(b2.y); hi.z = f2bf(b2.z); hi.w = f2bf(b2.w);
    u16* d = Wpk + (size_t)q * 8;
    *(ushort4*)d = lo;
    *(ushort4*)(d + 4) = hi;
  }
}

// ---------------------------------------------------------------------------
// Projection GEMM: C[m][n] = sum_k A[m][k]*Bm[n][k] + bias[n]
// PACK=0: C fp32 [M][N] row-major. PACK=1: pPk layout (strideC=81920).
// ---------------------------------------------------------------------------
template<int PACK>
__global__ void k_proj_gemm(const u16* __restrict__ A, const u16* __restrict__ Bm,
                            const float* __restrict__ bias, float* __restrict__ C,
                            int K, int N, size_t strideA, size_t strideC) {
  __shared__ __align__(16) u16 sA[64 * 64];
  __shared__ __align__(16) u16 sB[64 * 64];
  int bb = blockIdx.z;
  const u16* Ab = A + (size_t)bb * strideA;
  float* Cb = C + (size_t)bb * strideC;
  int m0 = blockIdx.x * 64, n0 = blockIdx.y * 64;
  int tid = threadIdx.x;
  int lane = tid & 63, wid = tid >> 6;

  f32x4 acc[2][2] = {};
  for (int kk = 0; kk < K; kk += 64) {
#pragma unroll
    for (int i = 0; i < 2; i++) {
      int c = tid + i * 256;
      int r = c >> 3, kc = c & 7;
      int s = (r << 3) | (kc ^ (r & 7));
      *(bf16x8*)(sA + s * 8) = *(const bf16x8*)(Ab + (size_t)(m0 + r) * K + kk + kc * 8);
      *(bf16x8*)(sB + s * 8) = *(const bf16x8*)(Bm + (size_t)(n0 + r) * K + kk + kc * 8);
    }
    __syncthreads();
    int wr = (wid >> 1) * 32, wc = (wid & 1) * 32;
    int lr = lane & 15, lk = lane >> 4;
#pragma unroll
    for (int ki = 0; ki < 2; ki++) {
      bf16x8 af[2], bq[2];
#pragma unroll
      for (int mf = 0; mf < 2; mf++) {
        int r = wr + mf * 16 + lr;
        int kc = ki * 4 + lk;
        int s = (r << 3) | (kc ^ (r & 7));
        af[mf] = *(const bf16x8*)(sA + s * 8);
      }
#pragma unroll
      for (int nf = 0; nf < 2; nf++) {
        int r = wc + nf * 16 + lr;
        int kc = ki * 4 + lk;
        int s = (r << 3) | (kc ^ (r & 7));
        bq[nf] = *(const bf16x8*)(sB + s * 8);
      }
#pragma unroll
      for (int mf = 0; mf < 2; mf++)
#pragma unroll
        for (int nf = 0; nf < 2; nf++)
          acc[mf][nf] = __builtin_amdgcn_mfma_f32_16x16x32_bf16(af[mf], bq[nf], acc[mf][nf], 0, 0, 0);
    }
    __syncthreads();
  }
  int wr = (wid >> 1) * 32, wc = (wid & 1) * 32;
  int lr = lane & 15, lq = lane >> 4;
#pragma unroll
  for (int nf = 0; nf < 2; nf++) {
    int n = n0 + wc + nf * 16 + lr;
    float bv = bias[n];
#pragma unroll
    for (int mf = 0; mf < 2; mf++) {
#pragma unroll
      for (int r = 0; r < 4; r++) {
        int m = m0 + wr + mf * 16 + lq * 4 + r;
        float v = acc[mf][nf][r] + bv;
        if (PACK)
          Cb[(size_t)(m >> 6) * 40960 + (n >> 2) * 256 + (m & 63) * 4 + (n & 3)] = v;
        else
          Cb[(size_t)m * N + n] = v;
      }
    }
  }
}

// ---------------------------------------------------------------------------
// Fused joint GEMM + bias + log_softmax (converged champion, rounds 12/14/17):
//   out[m][v] = log_softmax_v( relu(e[bt,:]+p[b,u,:]) . W_out[v,:] + b_out[v] )
// 64 rows x V=1024 per block (2048 blocks); 512 thr = 8 waves; wave wn owns
// cols [128wn,128wn+128). B streams to regs (dbuf, 1 tile ahead, wave-
// private cols -> per-wave vmcnt only). A built in LDS 2-tile chunks (one
// LGKM0+barrier per 2 tiles = all K-loop sync). mfma(bq, af) gives C^T
// fragments -> 32 dwordx4 stores + 2-shuffle row reduce.
// ABLATION LEDGER (all isolated, all regressed or null):
//   rotation ✗(r14) · persistence ✗✗✗(r11/r13/r16) · all-reg B+p ✗(r7)
//   free-run waves ✗(r10) · chunk-paired af ✗(r15) · 16-wave ✗(r18)
//   NT stores ✗(r19) · pack-fold ∅(r17) · swapped-MFMA ✓(r12, kept)
// ---------------------------------------------------------------------------
__global__ __launch_bounds__(512)
void k_fused7(const float* __restrict__ e, const float* __restrict__ pPk,
              const u16* __restrict__ Wpk, const float* __restrict__ bout,
              float* __restrict__ out) {
  __shared__ __align__(16) u16 sA[2][4096];    // [chunk][tin<2][koct<4][64 rows][8]
  __shared__ __align__(16) float sE[JH_];
  __shared__ float redm[512];
  __shared__ float reds[512];

  int bid = blockIdx.x;
  int btile = bid >> 1, half = bid & 1, b = btile >> 8;
  int tid = threadIdx.x, lane = tid & 63, wn = tid >> 6;
  int lr = lane & 15, lk = lane >> 4;

  const float* eRow = e + (size_t)btile * JH_;
  const float* pPbase = pPk + ((size_t)(b * 2 + half) * 40960) + wn * 256 + lane * 4;
  const u16* wB = Wpk + ((size_t)lk * 1024 + wn * 128 + lr) * 8;
  float* outB = out + ((size_t)btile * U_ + half * 64) * V_;

  // A-build: thread (wn=k-quad, lane=row) writes 4 bf16 at:
  int awr = (wn >> 1) * 512 + lane * 8 + (wn & 1) * 4;

  f32x4 acc[4][8] = {};
  bf16x8 bq[2][8];

  auto loadB = [&](int t, bf16x8* d) {
#pragma unroll
    for (int nf = 0; nf < 8; nf++)
      d[nf] = *(const bf16x8*)(wB + (size_t)t * 32768 + nf * 128);
  };
  auto loadp = [&](int t) { return *(const float4*)(pPbase + t * 2048); };
  auto build = [&](int slot, int tin, int t, float4 pv) {
    float4 ev = *(const float4*)(&sE[t * 32 + wn * 4]);
    uint2 w;
    w.x = cvt2(fmaxf(pv.x + ev.x, 0.f), fmaxf(pv.y + ev.y, 0.f));
    w.y = cvt2(fmaxf(pv.z + ev.z, 0.f), fmaxf(pv.w + ev.w, 0.f));
    *(uint2*)(&sA[slot][tin * 2048 + awr]) = w;
  };

  // ---- prologue
  loadB(0, bq[0]);                            // earliest possible issue
  for (int i = tid; i < JH_; i += 512) sE[i] = eRow[i];
  float4 p0  = loadp(0);
  float4 p1  = loadp(1);
  float4 pcA = loadp(2);
  float4 pcB = loadp(3);
  float4 pnA = p0, pnB = p0;                  // init to silence undef
  LGKM0;
  __builtin_amdgcn_s_barrier();               // sE visible
  build(0, 0, 0, p0);
  build(0, 1, 1, p1);
  LGKM0;
  __builtin_amdgcn_s_barrier();               // A chunk 0 visible

#pragma unroll
  for (int t = 0; t < KT_; t++) {
    if (t + 1 < KT_) loadB(t + 1, bq[(t + 1) & 1]);
    if ((t & 1) == 0) {
      if (t + 4 < KT_) { pnA = loadp(t + 4); pnB = loadp(t + 5); }
      if (t + 2 < KT_) {
        int q1 = ((t >> 1) + 1) & 1;
        build(q1, 0, t + 2, pcA);
        build(q1, 1, t + 3, pcB);
      }
    }
    const u16* Ab = &sA[(t >> 1) & 1][(t & 1) * 2048 + lk * 512];
    bf16x8 af[4];
#pragma unroll
    for (int mf = 0; mf < 4; mf++)
      af[mf] = *(const bf16x8*)(Ab + (mf * 16 + lr) * 8);
    __builtin_amdgcn_s_setprio(1);
#pragma unroll
    for (int mf = 0; mf < 4; mf++)
#pragma unroll
      for (int nf = 0; nf < 8; nf++)
        acc[mf][nf] = __builtin_amdgcn_mfma_f32_16x16x32_bf16(bq[t & 1][nf], af[mf], acc[mf][nf], 0, 0, 0);
    __builtin_amdgcn_s_setprio(0);
    if ((t & 1) && t + 1 < KT_) {             // chunk boundary
      pcA = pnA; pcB = pnB;
      LGKM0;                                  // drain builds of next chunk
      __builtin_amdgcn_s_barrier();
    }
  }

  // ---- epilogue: C^T frags: row m=mf*16+lr, cols n=wn*128+nf*16+lk*4+[0..3]
#pragma unroll
  for (int nf = 0; nf < 8; nf++) {
    f32x4 bv = *(const f32x4*)(bout + wn * 128 + nf * 16 + lk * 4);
#pragma unroll
    for (int mf = 0; mf < 4; mf++) acc[mf][nf] += bv;
  }
  float gm[4], lsv[4];
#pragma unroll
  for (int mf = 0; mf < 4; mf++) {
    float m = acc[mf][0][0];
#pragma unroll
    for (int nf = 0; nf < 8; nf++)
#pragma unroll
      for (int j = 0; j < 4; j++) m = fmaxf(m, acc[mf][nf][j]);
    m = fmaxf(m, __shfl_xor(m, 16, 64));
    m = fmaxf(m, __shfl_xor(m, 32, 64));
    gm[mf] = m;
  }
  if (lane < 16) {
#pragma unroll
    for (int mf = 0; mf < 4; mf++) redm[(mf * 16 + lr) * 8 + wn] = gm[mf];
  }
  __syncthreads();
#pragma unroll
  for (int mf = 0; mf < 4; mf++) {
    float m = redm[(mf * 16 + lr) * 8];
#pragma unroll
    for (int w = 1; w < 8; w++) m = fmaxf(m, redm[(mf * 16 + lr) * 8 + w]);
    gm[mf] = m;
  }
#pragma unroll
  for (int mf = 0; mf < 4; mf++) {
    float s = 0.f;
#pragma unroll
    for (int nf = 0; nf < 8; nf++)
#pragma unroll
      for (int j = 0; j < 4; j++) s += __expf(acc[mf][nf][j] - gm[mf]);
    s += __shfl_xor(s, 16, 64);
    s += __shfl_xor(s, 32, 64);
    lsv[mf] = s;
  }
  if (lane < 16) {
#pragma unroll
    for (int mf = 0; mf < 4; mf++) reds[(mf * 16 + lr) * 8 + wn] = lsv[mf];
  }
  __syncthreads();
#pragma unroll
  for (int mf = 0; mf < 4; mf++) {
    float s = reds[(mf * 16 + lr) * 8];
#pragma unroll
    for (int w = 1; w < 8; w++) s += reds[(mf * 16 + lr) * 8 + w];
    lsv[mf] = gm[mf] + __logf(s);
  }

  // ---- 32 x dwordx4 stores
#pragma unroll
  for (int mf = 0; mf < 4; mf++) {
    float* orow = outB + (size_t)(mf * 16 + lr) * V_ + wn * 128 + lk * 4;
#pragma unroll
    for (int nf = 0; nf < 8; nf++) {
      f32x4 v = acc[mf][nf] - lsv[mf];
      *(f32x4*)(orow + nf * 16) = v;
    }
  }
}

// ---------------------------------------------------------------------------
extern "C" void kernel_launch(void* const* d_in, const int* in_sizes, int n_in,
                              void* d_out, int out_size, void* d_ws, size_t ws_size,
                              hipStream_t stream) {
  const float* enc    = (const float*)d_in[0];
  const float* dec    = (const float*)d_in[1];
  const float* W_enc  = (const float*)d_in[2];
  const float* b_enc  = (const float*)d_in[3];
  const float* W_pred = (const float*)d_in[4];
  const float* b_pred = (const float*)d_in[5];
  const float* W_out  = (const float*)d_in[6];
  const float* b_out  = (const float*)d_in[7];
  float* out = (float*)d_out;

  char* ws = (char*)d_ws;
  size_t off = 0;
  auto alloc = [&](size_t bytes) {
    void* pp = ws + off;
    off = (off + bytes + 255) & ~(size_t)255;
    return pp;
  };
  u16* encT   = (u16*)alloc((size_t)B_ * T_ * EH_ * 2);
  u16* decT   = (u16*)alloc((size_t)B_ * U_ * PH_ * 2);
  u16* WencB  = (u16*)alloc((size_t)JH_ * EH_ * 2);
  u16* WpredB = (u16*)alloc((size_t)JH_ * PH_ * 2);
  u16* Wpk    = (u16*)alloc((size_t)KT_ * 32768 * 2);
  float* eBuf = (float*)alloc((size_t)B_ * T_ * JH_ * 4);
  float* pPk  = (float*)alloc((size_t)81920 * 4 * 4);

  // front-end
  k_transpose_cvt<<<dim3(T_ / 32, EH_ / 32, B_), 256, 0, stream>>>(enc, encT, EH_, T_);
  k_transpose_cvt<<<dim3(U_ / 32, PH_ / 32, B_), 256, 0, stream>>>(dec, decT, PH_, U_);
  k_prep_w<<<1360, 256, 0, stream>>>(W_enc, W_pred, W_out, WencB, WpredB, Wpk);
  k_proj_gemm<0><<<dim3(T_ / 64, JH_ / 64, B_), 256, 0, stream>>>(
      encT, WencB, b_enc, eBuf, EH_, JH_, (size_t)T_ * EH_, (size_t)T_ * JH_);
  // pred projection writes the packed pPk layout directly
  k_proj_gemm<1><<<dim3(U_ / 64, JH_ / 64, B_), 256, 0, stream>>>(
      decT, WpredB, b_pred, pPk, PH_, JH_, (size_t)U_ * PH_, (size_t)81920);

  // fused joint GEMM + log_softmax: one block per 64 output rows
  k_fused7<<<B_ * T_ * 2, 512, 0, stream>>>(eBuf, pPk, Wpk, b_out, out);
}